// Round 1
// baseline (20070.367 us; speedup 1.0000x reference)
//
#include <hip/hip_runtime.h>
#include <cstdint>

typedef _Float16 half8 __attribute__((ext_vector_type(8)));
typedef float floatx4 __attribute__((ext_vector_type(4)));
typedef unsigned long long u64;
typedef unsigned int u32;
typedef unsigned short u16;

#define NB 2048
#define NT 512
#define NH 256
#define NOUT 512
#define BTILE 16
#define NGRP 128   // batch groups (NB / BTILE)

__device__ __forceinline__ float fexp2(float x){ return __builtin_amdgcn_exp2f(x); }
__device__ __forceinline__ float frcp(float x){ return __builtin_amdgcn_rcpf(x); }
__device__ __forceinline__ float fsig(float x){ return frcp(1.0f + fexp2(-1.44269504f * x)); }
__device__ __forceinline__ float ftanh_(float x){ return 1.0f - 2.0f * frcp(1.0f + fexp2(2.88539008f * x)); }

// ---------------------------------------------------------------- setup ----
__global__ void setup_kernel(const float* __restrict__ Whh, const float* __restrict__ Wlin,
                             _Float16* __restrict__ Wpack, _Float16* __restrict__ WlinPack,
                             u16* __restrict__ hbuf0, int* __restrict__ flags)
{
    const int i = blockIdx.x * blockDim.x + threadIdx.x;
    const int stride = gridDim.x * blockDim.x;
    for (int k = i; k < 1024 * 256; k += stride) Wpack[k]    = (_Float16)Whh[k];
    for (int k = i; k < 512 * 256;  k += stride) WlinPack[k] = (_Float16)Wlin[k];
    for (int k = i; k < NB * NH;    k += stride) hbuf0[k]    = 0;
    for (int k = i; k < NGRP * 16;  k += stride) flags[k]    = 0;
}

// ----------------------------------------------------------------- lstm ----
// grid: 512 blocks = 128 batch-groups x 4 hidden-slices; block: 256 thr (4 waves)
// block (bg,hs): rows [bg*16, +16), units [hs*64, +64)
// wave wv owns units [hs*64 + wv*16, +16) for all 4 gates (i,f,g,o in-lane).
__global__ __launch_bounds__(256, 2)
void lstm_kernel(const float* __restrict__ x, const float* __restrict__ Wih,
                 const float* __restrict__ bih, const float* __restrict__ bhh,
                 const _Float16* __restrict__ Wpack,
                 u16* hbuf, u16* hlast, int* flags)
{
    __shared__ u16 ldsA[BTILE * NH];   // 8 KB, XOR-swizzled h tile
    __shared__ float xs[BTILE * NT];   // 32 KB x rows

    const int tid  = threadIdx.x;
    const int lane = tid & 63;
    const int wv   = tid >> 6;
    const int l15  = lane & 15;
    const int l4   = lane >> 4;
    const int bid  = blockIdx.x;
    const int bg   = bid >> 2;
    const int hs   = bid & 3;
    const int r0   = bg * BTILE;
    const int u0   = hs * 64 + wv * 16;

    // stage x rows for this group (once)
    {
        const floatx4* src = (const floatx4*)(x + (size_t)r0 * NT);
        floatx4* dst = (floatx4*)xs;
        #pragma unroll
        for (int i = 0; i < 8; i++) dst[tid + i * 256] = src[tid + i * 256];
    }

    // per-lane gate params + register-resident W_hh B-fragments (f16)
    float biasq[4], wihq[4];
    half8 bq[4][8];
    #pragma unroll
    for (int q = 0; q < 4; q++) {
        const int gq = q * 256 + u0 + l15;        // gate row in [0,1024)
        biasq[q] = bih[gq] + bhh[gq];
        wihq[q]  = Wih[gq];
        #pragma unroll
        for (int kc = 0; kc < 8; kc++)
            bq[q][kc] = *(const half8*)(Wpack + (size_t)gq * NH + kc * 32 + l4 * 8);
    }

    float c4[4] = {0.f, 0.f, 0.f, 0.f};
    int* flagsg = flags + bg * 16;

    for (int t = 0; t < NT; t++) {
        // wait until all peers have published h_t (flag >= t)
        if (tid < 4 && tid != hs) {
            while (__hip_atomic_load(flagsg + tid, __ATOMIC_RELAXED, __HIP_MEMORY_SCOPE_AGENT) < t)
                __builtin_amdgcn_s_sleep(1);
        }
        __syncthreads();

        // stage h_t tile -> LDS (agent-scope loads bypass stale L1/L2)
        {
            u64* src = (u64*)(hbuf + (size_t)(t & 1) * NB * NH + (size_t)r0 * NH);
            #pragma unroll
            for (int i = 0; i < 4; i++) {
                const int uidx = tid * 16 + i * 4;          // ushort index in tile
                const u64 v = __hip_atomic_load(src + tid * 4 + i, __ATOMIC_RELAXED, __HIP_MEMORY_SCOPE_AGENT);
                const int row = uidx >> 8;
                const int kk  = uidx & 255;
                *(u64*)(ldsA + row * 256 + (kk ^ ((row & 7) << 3))) = v;
            }
        }
        __syncthreads();

        // A fragments: lane holds h[row=l15][k = kc*32 + l4*8 .. +8)
        half8 a[8];
        #pragma unroll
        for (int kc = 0; kc < 8; kc++) {
            const int ks = kc * 32 + l4 * 8;
            a[kc] = *(const half8*)(ldsA + l15 * 256 + (ks ^ ((l15 & 7) << 3)));
        }

        // gates = h @ W_slice^T + bias (fp32 accum, bias preloaded into C)
        floatx4 acc[4];
        #pragma unroll
        for (int q = 0; q < 4; q++)
            acc[q] = (floatx4){biasq[q], biasq[q], biasq[q], biasq[q]};
        #pragma unroll
        for (int kc = 0; kc < 8; kc++) {
            #pragma unroll
            for (int q = 0; q < 4; q++)
                acc[q] = __builtin_amdgcn_mfma_f32_16x16x32_f16(a[kc], bq[q][kc], acc[q], 0, 0, 0);
        }

        // pointwise LSTM update; c stays fp32 in registers
        u16* dst = (t == NT - 1) ? hlast : (hbuf + (size_t)((t + 1) & 1) * NB * NH);
        #pragma unroll
        for (int j = 0; j < 4; j++) {
            const int row = l4 * 4 + j;
            const float xv = xs[row * NT + t];
            const float pi = acc[0][j] + xv * wihq[0];
            const float pf = acc[1][j] + xv * wihq[1];
            const float pg = acc[2][j] + xv * wihq[2];
            const float po = acc[3][j] + xv * wihq[3];
            const float ig = fsig(pi);
            const float fg = fsig(pf);
            const float gg = ftanh_(pg);
            const float og = fsig(po);
            const float c  = fg * c4[j] + ig * gg;
            c4[j] = c;
            const float h  = og * ftanh_(c);
            const u16 bits = __builtin_bit_cast(u16, (_Float16)h);
            const u32 ob   = (u16)__shfl_xor((int)bits, 1, 64);   // partner lane's f16
            if ((lane & 1) == 0) {                                 // pack 2 units -> 4B store
                const u32 packed = (u32)bits | (ob << 16);
                const size_t widx = ((size_t)(r0 + row) * NH + u0 + l15) >> 1;
                __hip_atomic_store((u32*)dst + widx, packed, __ATOMIC_RELAXED, __HIP_MEMORY_SCOPE_AGENT);
            }
        }
        __threadfence();        // drain this wave's h stores
        __syncthreads();        // all waves drained
        if (tid == 0)
            __hip_atomic_store(flagsg + hs, t + 1, __ATOMIC_RELEASE, __HIP_MEMORY_SCOPE_AGENT);
    }
}

// --------------------------------------------------------------- linear ----
// out[2048,512] = h_last(f16) @ W_lin^T + b_lin, f16 MFMA, fp32 out
__global__ __launch_bounds__(256, 2)
void linear_kernel(const u16* __restrict__ hlast_u, const _Float16* __restrict__ WlinPack,
                   const float* __restrict__ blin, float* __restrict__ out)
{
    const int tid = threadIdx.x;
    const int lane = tid & 63;
    const int wv = tid >> 6;
    const int mi = wv >> 1, ni = wv & 1;
    const int l15 = lane & 15, l4 = lane >> 4;
    const int r0 = (blockIdx.x >> 3) * 32;
    const int o0 = (blockIdx.x & 7) * 64;
    const _Float16* hl = (const _Float16*)hlast_u;
    const int arow = r0 + mi * 16 + l15;

    half8 a[8];
    #pragma unroll
    for (int kc = 0; kc < 8; kc++)
        a[kc] = *(const half8*)(hl + (size_t)arow * NH + kc * 32 + l4 * 8);

    #pragma unroll
    for (int nt = 0; nt < 2; nt++) {
        const int col = o0 + ni * 32 + nt * 16 + l15;
        floatx4 acc = (floatx4){0.f, 0.f, 0.f, 0.f};
        #pragma unroll
        for (int kc = 0; kc < 8; kc++) {
            const half8 b = *(const half8*)(WlinPack + (size_t)col * NH + kc * 32 + l4 * 8);
            acc = __builtin_amdgcn_mfma_f32_16x16x32_f16(a[kc], b, acc, 0, 0, 0);
        }
        const float bb = blin[col];
        #pragma unroll
        for (int j = 0; j < 4; j++) {
            const int row = r0 + mi * 16 + l4 * 4 + j;
            out[(size_t)row * NOUT + col] = acc[j] + bb;
        }
    }
}

// --------------------------------------------------------------- launch ----
extern "C" void kernel_launch(void* const* d_in, const int* in_sizes, int n_in,
                              void* d_out, int out_size, void* d_ws, size_t ws_size,
                              hipStream_t stream)
{
    const float* x    = (const float*)d_in[0];
    const float* Wih  = (const float*)d_in[1];
    const float* Whh  = (const float*)d_in[2];
    const float* bih  = (const float*)d_in[3];
    const float* bhh  = (const float*)d_in[4];
    const float* Wlin = (const float*)d_in[5];
    const float* blin = (const float*)d_in[6];

    char* ws = (char*)d_ws;
    _Float16* Wpack    = (_Float16*)(ws);                 // 512 KB
    _Float16* WlinPack = (_Float16*)(ws + (512 << 10));   // 256 KB
    u16*      hlast    = (u16*)(ws + (768 << 10));        // 1 MB
    int*      flags    = (int*)(ws + (1792 << 10));       // 8 KB
    u16*      hbuf     = (u16*)d_out;  // 2x1MB h ping-pong inside the 4MB out buffer

    setup_kernel<<<256, 256, 0, stream>>>(Whh, Wlin, Wpack, WlinPack, hbuf, flags);
    lstm_kernel<<<512, 256, 0, stream>>>(x, Wih, bih, bhh, Wpack, hbuf, hlast, flags);
    linear_kernel<<<512, 256, 0, stream>>>(hlast, WlinPack, blin, (float*)d_out);
}

// Round 2
// 2938.052 us; speedup vs baseline: 6.8312x; 6.8312x over previous
//
#include <hip/hip_runtime.h>
#include <cstdint>

typedef _Float16 half8 __attribute__((ext_vector_type(8)));
typedef float floatx4 __attribute__((ext_vector_type(4)));
typedef unsigned long long u64;
typedef unsigned int u32;
typedef unsigned short u16;

#define NB 2048
#define NT 512
#define NH 256
#define NOUT 512
#define BTILE 16

template<int N> struct ic { static constexpr int value = N; };

__device__ __forceinline__ float fexp2(float x){ return __builtin_amdgcn_exp2f(x); }
__device__ __forceinline__ float frcp(float x){ return __builtin_amdgcn_rcpf(x); }
__device__ __forceinline__ float fsig(float x){ return frcp(1.0f + fexp2(-1.44269504f * x)); }
__device__ __forceinline__ float ftanh_(float x){ return 1.0f - 2.0f * frcp(1.0f + fexp2(2.88539008f * x)); }

__device__ __forceinline__ floatx4 mfma16(half8 a, half8 b, floatx4 c) {
    return __builtin_amdgcn_mfma_f32_16x16x32_f16(a, b, c, 0, 0, 0);
}

// ---------------------------------------------------------------- setup ----
__global__ void setup_kernel(const float* __restrict__ Whh, const float* __restrict__ Wlin,
                             _Float16* __restrict__ Wpack, _Float16* __restrict__ WlinPack)
{
    const int i = blockIdx.x * blockDim.x + threadIdx.x;
    const int stride = gridDim.x * blockDim.x;
    for (int k = i; k < 1024 * 256; k += stride) Wpack[k]    = (_Float16)Whh[k];
    for (int k = i; k < 512 * 256;  k += stride) WlinPack[k] = (_Float16)Wlin[k];
}

// ----------------------------------------------------------------- lstm ----
// 128 blocks x 256 threads. Block b: batch rows [b*16, +16), FULL 256-unit state.
// Wave wv owns units [wv*64, +64) as 4 unit-groups (ug) of 16.
// W_hh tile (ug,q) sourcing per wave: ug0-2/q0-2 -> registers (9 tiles, 288 VGPR);
// ug0-2/q3 -> streamed from L2 (2 rotating half8[8] buffers); ug3/q* -> LDS (128KB).
// h state lives ONLY in LDS (8KB, XOR-swizzled); 2 barriers per step; no atomics.
__global__ __launch_bounds__(256, 1)
void lstm_kernel(const float* __restrict__ x, const float* __restrict__ Wih,
                 const float* __restrict__ bih, const float* __restrict__ bhh,
                 const _Float16* __restrict__ Wpack, u16* __restrict__ hlast)
{
    __shared__ __align__(16) u16 wlds[16][16 * 256];   // 128 KB: tiles (ug==3), id = wv*4+q
    __shared__ __align__(16) u16 hlds[16 * 256];       // 8 KB h tile, swizzled
    __shared__ float biaslds[1024];                    // 4 KB  b_ih+b_hh
    __shared__ float wihlds[1024];                     // 4 KB  W_ih

    const int tid  = threadIdx.x;
    const int lane = tid & 63;
    const int wv   = tid >> 6;
    const int l15  = lane & 15;
    const int l4   = lane >> 4;
    const int r0   = blockIdx.x * BTILE;
    const int u0   = wv * 64;

    // ---- prologue ----
    for (int g = tid; g < 1024; g += 256) { biaslds[g] = bih[g] + bhh[g]; wihlds[g] = Wih[g]; }
    for (int i = tid; i < 1024; i += 256) ((u64*)hlds)[i] = 0;  // h_0 = 0

    // stage LDS-resident W tiles (ug==3) with XOR swizzle
    for (int ch = tid; ch < 8192; ch += 256) {
        const int tl = ch >> 9;            // tile 0..15 (= w*4+q)
        const int r  = (ch >> 5) & 15;     // row in tile
        const int ks = (ch & 31) * 8;      // u16 col start (16B chunks)
        const int w_ = tl >> 2, q_ = tl & 3;
        const int G  = q_ * 256 + w_ * 64 + 48 + r;
        half8 v = *(const half8*)(Wpack + (size_t)G * NH + ks);
        *(half8*)(&wlds[tl][r * 256 + (ks ^ ((r & 7) << 3))]) = v;
    }

    // register-resident W tiles: (ug 0..2) x (q 0..2)
    half8 wreg[3][3][8];
    #pragma unroll
    for (int ug = 0; ug < 3; ug++)
        #pragma unroll
        for (int q = 0; q < 3; q++) {
            const int G = q * 256 + u0 + ug * 16 + l15;
            #pragma unroll
            for (int kc = 0; kc < 8; kc++)
                wreg[ug][q][kc] = *(const half8*)(Wpack + (size_t)G * NH + kc * 32 + l4 * 8);
        }

    // stream buffers: prefetch S(ug=0)->sb[0], S(ug=1)->sb[1]  (q==3 tiles)
    half8 sb[2][8];
    #pragma unroll
    for (int kc = 0; kc < 8; kc++)
        sb[0][kc] = *(const half8*)(Wpack + (size_t)(768 + u0 + 0 * 16 + l15) * NH + kc * 32 + l4 * 8);
    #pragma unroll
    for (int kc = 0; kc < 8; kc++)
        sb[1][kc] = *(const half8*)(Wpack + (size_t)(768 + u0 + 1 * 16 + l15) * NH + kc * 32 + l4 * 8);

    float c16[16];
    #pragma unroll
    for (int i = 0; i < 16; i++) c16[i] = 0.f;

    __syncthreads();

    // one timestep; BX/BY select stream-buffer roles (swap every step)
    auto step = [&](int t, auto bxc, auto byc) {
        constexpr int BX = decltype(bxc)::value;
        constexpr int BY = decltype(byc)::value;
        const bool last = (t == NT - 1);

        float xv[4];
        #pragma unroll
        for (int j = 0; j < 4; j++)
            xv[j] = x[(size_t)(r0 + l4 * 4 + j) * NT + t];

        half8 a[8];
        #pragma unroll
        for (int kc = 0; kc < 8; kc++) {
            const int ks = kc * 32 + l4 * 8;
            a[kc] = *(const half8*)(&hlds[l15 * 256 + (ks ^ ((l15 & 7) << 3))]);
        }
        __syncthreads();   // barrier1: all h_t reads done before any h_{t+1} write

        // process unit-group UG (0..2): q0-2 from wreg, q3 from stream buffer s3
        auto do_ug = [&](auto ugc, half8 (&s3)[8]) {
            constexpr int UG = decltype(ugc)::value;
            floatx4 acc[4];
            #pragma unroll
            for (int q = 0; q < 4; q++) {
                const int gi = q * 256 + u0 + UG * 16 + l15;
                const float b = biaslds[gi], wi = wihlds[gi];
                #pragma unroll
                for (int j = 0; j < 4; j++) acc[q][j] = b + xv[j] * wi;
            }
            #pragma unroll
            for (int kc = 0; kc < 8; kc++) {
                acc[0] = mfma16(a[kc], wreg[UG][0][kc], acc[0]);
                acc[1] = mfma16(a[kc], wreg[UG][1][kc], acc[1]);
                acc[2] = mfma16(a[kc], wreg[UG][2][kc], acc[2]);
                acc[3] = mfma16(a[kc], s3[kc], acc[3]);
            }
            #pragma unroll
            for (int j = 0; j < 4; j++) {
                const float ig = fsig(acc[0][j]);
                const float fg = fsig(acc[1][j]);
                const float gg = ftanh_(acc[2][j]);
                const float og = fsig(acc[3][j]);
                float cc = c16[UG * 4 + j];
                cc = fg * cc + ig * gg;
                c16[UG * 4 + j] = cc;
                const float h = og * ftanh_(cc);
                const int row = l4 * 4 + j;
                const int unit = u0 + UG * 16 + l15;
                const u16 hb = __builtin_bit_cast(u16, (_Float16)h);
                hlds[row * 256 + (unit ^ ((row & 7) << 3))] = hb;
                if (last) hlast[(size_t)(r0 + row) * NH + unit] = hb;
            }
        };

        do_ug(ic<0>{}, sb[BX]);
        #pragma unroll   // reload: S(ug=2) -> sb[BX]  (consumed at ug2 this step)
        for (int kc = 0; kc < 8; kc++)
            sb[BX][kc] = *(const half8*)(Wpack + (size_t)(768 + u0 + 2 * 16 + l15) * NH + kc * 32 + l4 * 8);

        do_ug(ic<1>{}, sb[BY]);
        #pragma unroll   // reload: S(ug=0) -> sb[BY]  (consumed at ug0 next step)
        for (int kc = 0; kc < 8; kc++)
            sb[BY][kc] = *(const half8*)(Wpack + (size_t)(768 + u0 + 0 * 16 + l15) * NH + kc * 32 + l4 * 8);

        do_ug(ic<2>{}, sb[BX]);
        #pragma unroll   // reload: S(ug=1) -> sb[BX]  (consumed at ug1 next step)
        for (int kc = 0; kc < 8; kc++)
            sb[BX][kc] = *(const half8*)(Wpack + (size_t)(768 + u0 + 1 * 16 + l15) * NH + kc * 32 + l4 * 8);

        // unit-group 3: all four q-tiles from LDS
        {
            floatx4 acc[4];
            #pragma unroll
            for (int q = 0; q < 4; q++) {
                const int gi = q * 256 + u0 + 48 + l15;
                const float b = biaslds[gi], wi = wihlds[gi];
                #pragma unroll
                for (int j = 0; j < 4; j++) acc[q][j] = b + xv[j] * wi;
            }
            #pragma unroll
            for (int kc = 0; kc < 8; kc++) {
                const int ks = kc * 32 + l4 * 8;
                const int so = (ks ^ ((l15 & 7) << 3));
                #pragma unroll
                for (int q = 0; q < 4; q++) {
                    const half8 b = *(const half8*)(&wlds[wv * 4 + q][l15 * 256 + so]);
                    acc[q] = mfma16(a[kc], b, acc[q]);
                }
            }
            #pragma unroll
            for (int j = 0; j < 4; j++) {
                const float ig = fsig(acc[0][j]);
                const float fg = fsig(acc[1][j]);
                const float gg = ftanh_(acc[2][j]);
                const float og = fsig(acc[3][j]);
                float cc = c16[12 + j];
                cc = fg * cc + ig * gg;
                c16[12 + j] = cc;
                const float h = og * ftanh_(cc);
                const int row = l4 * 4 + j;
                const int unit = u0 + 48 + l15;
                const u16 hb = __builtin_bit_cast(u16, (_Float16)h);
                hlds[row * 256 + (unit ^ ((row & 7) << 3))] = hb;
                if (last) hlast[(size_t)(r0 + row) * NH + unit] = hb;
            }
        }
        __syncthreads();   // barrier2: h_{t+1} complete before next step's reads
    };

    for (int t = 0; t < NT; t += 2) {
        step(t,     ic<0>{}, ic<1>{});
        step(t + 1, ic<1>{}, ic<0>{});
    }
}

// --------------------------------------------------------------- linear ----
// out[2048,512] = h_last(f16) @ W_lin^T + b_lin
__global__ __launch_bounds__(256, 2)
void linear_kernel(const u16* __restrict__ hlast_u, const _Float16* __restrict__ WlinPack,
                   const float* __restrict__ blin, float* __restrict__ out)
{
    const int tid = threadIdx.x;
    const int lane = tid & 63;
    const int wv = tid >> 6;
    const int mi = wv >> 1, ni = wv & 1;
    const int l15 = lane & 15, l4 = lane >> 4;
    const int r0 = (blockIdx.x >> 3) * 32;
    const int o0 = (blockIdx.x & 7) * 64;
    const _Float16* hl = (const _Float16*)hlast_u;
    const int arow = r0 + mi * 16 + l15;

    half8 a[8];
    #pragma unroll
    for (int kc = 0; kc < 8; kc++)
        a[kc] = *(const half8*)(hl + (size_t)arow * NH + kc * 32 + l4 * 8);

    #pragma unroll
    for (int nt = 0; nt < 2; nt++) {
        const int col = o0 + ni * 32 + nt * 16 + l15;
        floatx4 acc = (floatx4){0.f, 0.f, 0.f, 0.f};
        #pragma unroll
        for (int kc = 0; kc < 8; kc++) {
            const half8 b = *(const half8*)(WlinPack + (size_t)col * NH + kc * 32 + l4 * 8);
            acc = mfma16(a[kc], b, acc);
        }
        const float bb = blin[col];
        #pragma unroll
        for (int j = 0; j < 4; j++) {
            const int row = r0 + mi * 16 + l4 * 4 + j;
            out[(size_t)row * NOUT + col] = acc[j] + bb;
        }
    }
}

// --------------------------------------------------------------- launch ----
extern "C" void kernel_launch(void* const* d_in, const int* in_sizes, int n_in,
                              void* d_out, int out_size, void* d_ws, size_t ws_size,
                              hipStream_t stream)
{
    const float* x    = (const float*)d_in[0];
    const float* Wih  = (const float*)d_in[1];
    const float* Whh  = (const float*)d_in[2];
    const float* bih  = (const float*)d_in[3];
    const float* bhh  = (const float*)d_in[4];
    const float* Wlin = (const float*)d_in[5];
    const float* blin = (const float*)d_in[6];

    char* ws = (char*)d_ws;
    _Float16* Wpack    = (_Float16*)(ws);                 // 512 KB
    _Float16* WlinPack = (_Float16*)(ws + (512 << 10));   // 256 KB
    u16*      hlast    = (u16*)(ws + (768 << 10));        // 1 MB

    setup_kernel<<<256, 256, 0, stream>>>(Whh, Wlin, Wpack, WlinPack);
    lstm_kernel<<<128, 256, 0, stream>>>(x, Wih, bih, bhh, Wpack, hlast);
    linear_kernel<<<512, 256, 0, stream>>>(hlast, WlinPack, blin, (float*)d_out);
}

// Round 3
// 1853.183 us; speedup vs baseline: 10.8302x; 1.5854x over previous
//
#include <hip/hip_runtime.h>
#include <cstdint>

typedef _Float16 half8 __attribute__((ext_vector_type(8)));
typedef float floatx4 __attribute__((ext_vector_type(4)));
typedef unsigned long long u64;
typedef unsigned int u32;
typedef unsigned short u16;

#define NB 2048
#define NT 512
#define NH 256
#define NOUT 512

#define LOG2E 1.4426950408889634f
#define TWOL  2.8853900817779268f

__device__ __forceinline__ float fexp2(float x){ return __builtin_amdgcn_exp2f(x); }
__device__ __forceinline__ float frcp(float x){ return __builtin_amdgcn_rcpf(x); }

__device__ __forceinline__ floatx4 mfma16(half8 a, half8 b, floatx4 c) {
    return __builtin_amdgcn_mfma_f32_16x16x32_f16(a, b, c, 0, 0, 0);
}

// ---------------------------------------------------------------- setup ----
__global__ void setup_kernel(const float* __restrict__ Whh, const float* __restrict__ Wlin,
                             _Float16* __restrict__ Wpack, _Float16* __restrict__ WlinPack)
{
    const int i = blockIdx.x * blockDim.x + threadIdx.x;
    const int stride = gridDim.x * blockDim.x;
    for (int k = i; k < 1024 * 256; k += stride) Wpack[k]    = (_Float16)Whh[k];
    for (int k = i; k < 512 * 256;  k += stride) WlinPack[k] = (_Float16)Wlin[k];
}

// xT[t][b] = x[b][t]  (tiled transpose, 32x32 tiles, 256 thr = 32x8)
__global__ void transpose_kernel(const float* __restrict__ x, float* __restrict__ xT)
{
    __shared__ float tile[32][33];
    const int tx = threadIdx.x & 31, ty = threadIdx.x >> 5;
    const int t0 = blockIdx.x * 32;   // 16 tiles along T
    const int b0 = blockIdx.y * 32;   // 64 tiles along B
    #pragma unroll
    for (int i = 0; i < 4; i++)
        tile[ty + 8 * i][tx] = x[(size_t)(b0 + ty + 8 * i) * NT + t0 + tx];
    __syncthreads();
    #pragma unroll
    for (int i = 0; i < 4; i++)
        xT[(size_t)(t0 + ty + 8 * i) * NB + b0 + tx] = tile[tx][ty + 8 * i];
}

// ----------------------------------------------------------------- lstm ----
// 128 blocks x 512 threads (8 waves, 2 waves/SIMD). Block: 16 rows, full 256 units.
// Wave wv owns units [wv*32, +32) = 2 unit-groups(ug) x 16, x 4 gates = 8 W-tiles:
//   q=0..2 (i,f,g) register-resident (6 tiles, 192 VGPR); q=3 (o) in LDS (16 tiles, 128KB).
// h double-buffered in LDS (2x8KB) -> ONE barrier/step, no read/write race.
__global__ __launch_bounds__(512, 2)
void lstm_kernel(const float* __restrict__ xT, const float* __restrict__ Wih,
                 const float* __restrict__ bih, const float* __restrict__ bhh,
                 const _Float16* __restrict__ Wpack, u16* __restrict__ hlast)
{
    __shared__ __align__(16) u16 wlds[16][4096];   // 128 KB  o-gate tiles, id = wv*2+ug
    __shared__ __align__(16) u16 hlds[2][4096];    // 16 KB   h ping-pong, XOR-swizzled
    __shared__ float2 bwlds[1024];                 // 8 KB    {b_ih+b_hh, W_ih} per gate-row

    const int tid  = threadIdx.x;
    const int lane = tid & 63;
    const int wv   = tid >> 6;     // 0..7
    const int l15  = lane & 15;
    const int l4   = lane >> 4;
    const int r0   = blockIdx.x * 16;
    const int u0   = wv * 32;

    // ---- prologue ----
    for (int g = tid; g < 1024; g += 512) bwlds[g] = make_float2(bih[g] + bhh[g], Wih[g]);
    for (int i = tid; i < 1024; i += 512) ((u64*)hlds[0])[i] = 0;   // h_0 = 0

    // stage o-gate tiles into LDS (swizzled)
    for (int ch = tid; ch < 8192; ch += 512) {
        const int tl = ch >> 9;            // tile 0..15 (= wv*2+ug)
        const int r  = (ch >> 5) & 15;     // row (unit) in tile
        const int ks = (ch & 31) * 8;      // u16 col start
        const int G  = 768 + (tl >> 1) * 32 + (tl & 1) * 16 + r;
        half8 v = *(const half8*)(Wpack + (size_t)G * NH + ks);
        *(half8*)(&wlds[tl][r * 256 + (ks ^ ((r & 7) << 3))]) = v;
    }

    // register-resident W tiles: ug x {i,f,g}
    half8 wreg[2][3][8];
    #pragma unroll
    for (int ug = 0; ug < 2; ug++)
        #pragma unroll
        for (int q = 0; q < 3; q++) {
            const int G = q * 256 + u0 + ug * 16 + l15;
            #pragma unroll
            for (int kc = 0; kc < 8; kc++)
                wreg[ug][q][kc] = *(const half8*)(Wpack + (size_t)G * NH + kc * 32 + l4 * 8);
        }

    float cst[8];
    #pragma unroll
    for (int i = 0; i < 8; i++) cst[i] = 0.f;

    __syncthreads();

    for (int t = 0; t < NT; t++) {
        const u16* hsrc = hlds[t & 1];
        u16*       hdst = hlds[(t + 1) & 1];
        const floatx4 xv = *(const floatx4*)(xT + (size_t)t * NB + r0 + l4 * 4);

        #pragma unroll
        for (int ug = 0; ug < 2; ug++) {
            floatx4 acc[4];
            #pragma unroll
            for (int q = 0; q < 4; q++) {
                const float2 bw = bwlds[q * 256 + u0 + ug * 16 + l15];
                #pragma unroll
                for (int j = 0; j < 4; j++) acc[q][j] = bw.x + xv[j] * bw.y;
            }
            #pragma unroll
            for (int half_ = 0; half_ < 2; half_++) {
                half8 a[4];
                #pragma unroll
                for (int k2 = 0; k2 < 4; k2++) {
                    const int ks = (half_ * 4 + k2) * 32 + l4 * 8;
                    a[k2] = *(const half8*)(hsrc + l15 * 256 + (ks ^ ((l15 & 7) << 3)));
                }
                #pragma unroll
                for (int k2 = 0; k2 < 4; k2++) {
                    const int kc = half_ * 4 + k2;
                    const int ks = kc * 32 + l4 * 8;
                    acc[0] = mfma16(a[k2], wreg[ug][0][kc], acc[0]);
                    acc[1] = mfma16(a[k2], wreg[ug][1][kc], acc[1]);
                    acc[2] = mfma16(a[k2], wreg[ug][2][kc], acc[2]);
                    const half8 b3 = *(const half8*)(&wlds[wv * 2 + ug][l15 * 256 + (ks ^ ((l15 & 7) << 3))]);
                    acc[3] = mfma16(a[k2], b3, acc[3]);
                }
            }
            // folded pointwise: i*g = (eg-1)/((eg+1)(1+ei)); h = (ec-1)/((ec+1)(1+eo))
            #pragma unroll
            for (int j = 0; j < 4; j++) {
                const float pi = acc[0][j], pf = acc[1][j], pg = acc[2][j], po = acc[3][j];
                const float ei = fexp2(-LOG2E * pi);
                const float ef = fexp2(-LOG2E * pf);
                const float eo = fexp2(-LOG2E * po);
                const float eg = fexp2(TWOL * pg);               // |pg| < 18 -> no overflow
                const float f  = frcp(1.f + ef);
                const float ig = (eg - 1.f) * frcp((eg + 1.f) * (1.f + ei));
                const float cc = f * cst[ug * 4 + j] + ig;
                cst[ug * 4 + j] = cc;
                const float ec = fexp2(fminf(TWOL * cc, 126.f)); // c can grow -> clamp
                const float h  = (ec - 1.f) * frcp((ec + 1.f) * (1.f + eo));
                const int row  = l4 * 4 + j;
                const int unit = u0 + ug * 16 + l15;
                hdst[row * 256 + (unit ^ ((row & 7) << 3))] = __builtin_bit_cast(u16, (_Float16)h);
            }
        }
        __syncthreads();   // h_{t+1} complete; next step reads the other buffer
    }

    // h_T lives in hlds[0] (t=511 wrote buffer (512)&1 == 0)
    for (int i = tid; i < 4096; i += 512) {
        const int row = i >> 8, unit = i & 255;
        hlast[(size_t)(r0 + row) * NH + unit] = hlds[0][row * 256 + (unit ^ ((row & 7) << 3))];
    }
}

// --------------------------------------------------------------- linear ----
// out[2048,512] = h_last(f16) @ W_lin^T + b_lin
__global__ __launch_bounds__(256, 2)
void linear_kernel(const u16* __restrict__ hlast_u, const _Float16* __restrict__ WlinPack,
                   const float* __restrict__ blin, float* __restrict__ out)
{
    const int tid = threadIdx.x;
    const int lane = tid & 63;
    const int wv = tid >> 6;
    const int mi = wv >> 1, ni = wv & 1;
    const int l15 = lane & 15, l4 = lane >> 4;
    const int r0 = (blockIdx.x >> 3) * 32;
    const int o0 = (blockIdx.x & 7) * 64;
    const _Float16* hl = (const _Float16*)hlast_u;
    const int arow = r0 + mi * 16 + l15;

    half8 a[8];
    #pragma unroll
    for (int kc = 0; kc < 8; kc++)
        a[kc] = *(const half8*)(hl + (size_t)arow * NH + kc * 32 + l4 * 8);

    #pragma unroll
    for (int nt = 0; nt < 2; nt++) {
        const int col = o0 + ni * 32 + nt * 16 + l15;
        floatx4 acc = (floatx4){0.f, 0.f, 0.f, 0.f};
        #pragma unroll
        for (int kc = 0; kc < 8; kc++) {
            const half8 b = *(const half8*)(WlinPack + (size_t)col * NH + kc * 32 + l4 * 8);
            acc = mfma16(a[kc], b, acc);
        }
        const float bb = blin[col];
        #pragma unroll
        for (int j = 0; j < 4; j++) {
            const int row = r0 + mi * 16 + l4 * 4 + j;
            out[(size_t)row * NOUT + col] = acc[j] + bb;
        }
    }
}

// --------------------------------------------------------------- launch ----
extern "C" void kernel_launch(void* const* d_in, const int* in_sizes, int n_in,
                              void* d_out, int out_size, void* d_ws, size_t ws_size,
                              hipStream_t stream)
{
    const float* x    = (const float*)d_in[0];
    const float* Wih  = (const float*)d_in[1];
    const float* Whh  = (const float*)d_in[2];
    const float* bih  = (const float*)d_in[3];
    const float* bhh  = (const float*)d_in[4];
    const float* Wlin = (const float*)d_in[5];
    const float* blin = (const float*)d_in[6];

    char* ws = (char*)d_ws;
    _Float16* Wpack    = (_Float16*)(ws);                 // 512 KB
    _Float16* WlinPack = (_Float16*)(ws + (512 << 10));   // 256 KB
    u16*      hlast    = (u16*)(ws + (768 << 10));        // 1 MB
    float*    xT       = (float*)d_out;                   // 4 MB scratch until linear overwrites

    setup_kernel<<<256, 256, 0, stream>>>(Whh, Wlin, Wpack, WlinPack);
    transpose_kernel<<<dim3(16, 64), 256, 0, stream>>>(x, xT);
    lstm_kernel<<<128, 512, 0, stream>>>(xT, Wih, bih, bhh, Wpack, hlast);
    linear_kernel<<<512, 256, 0, stream>>>(hlast, WlinPack, blin, (float*)d_out);
}

// Round 5
// 1851.427 us; speedup vs baseline: 10.8405x; 1.0009x over previous
//
#include <hip/hip_runtime.h>
#include <cstdint>

typedef _Float16 half8 __attribute__((ext_vector_type(8)));
typedef float floatx4 __attribute__((ext_vector_type(4)));
typedef unsigned long long u64;
typedef unsigned int u32;
typedef unsigned short u16;

#define NB 2048
#define NT 512
#define NH 256
#define NOUT 512

#define LOG2E 1.4426950408889634f
#define TWOL  2.8853900817779268f

__device__ __forceinline__ float fexp2(float x){ return __builtin_amdgcn_exp2f(x); }
__device__ __forceinline__ float frcp(float x){ return __builtin_amdgcn_rcpf(x); }

__device__ __forceinline__ floatx4 mfma16(half8 a, half8 b, floatx4 c) {
    return __builtin_amdgcn_mfma_f32_16x16x32_f16(a, b, c, 0, 0, 0);
}

// ---------------------------------------------------------------- setup ----
__global__ void setup_kernel(const float* __restrict__ Whh, const float* __restrict__ Wlin,
                             _Float16* __restrict__ Wpack, _Float16* __restrict__ WlinPack)
{
    const int i = blockIdx.x * blockDim.x + threadIdx.x;
    const int stride = gridDim.x * blockDim.x;
    for (int k = i; k < 1024 * 256; k += stride) Wpack[k]    = (_Float16)Whh[k];
    for (int k = i; k < 512 * 256;  k += stride) WlinPack[k] = (_Float16)Wlin[k];
}

// xT[t][b] = x[b][t]  (tiled transpose, 32x32 tiles, 256 thr = 32x8)
__global__ void transpose_kernel(const float* __restrict__ x, float* __restrict__ xT)
{
    __shared__ float tile[32][33];
    const int tx = threadIdx.x & 31, ty = threadIdx.x >> 5;
    const int t0 = blockIdx.x * 32;   // 16 tiles along T
    const int b0 = blockIdx.y * 32;   // 64 tiles along B
    #pragma unroll
    for (int i = 0; i < 4; i++)
        tile[ty + 8 * i][tx] = x[(size_t)(b0 + ty + 8 * i) * NT + t0 + tx];
    __syncthreads();
    #pragma unroll
    for (int i = 0; i < 4; i++)
        xT[(size_t)(t0 + ty + 8 * i) * NB + b0 + tx] = tile[tx][ty + 8 * i];
}

// ----------------------------------------------------------------- lstm ----
// 128 blocks x 512 threads (8 waves, 2 waves/SIMD). Block: 16 rows, full 256 units.
// Wave wv owns units [wv*32, +32) = 2 unit-groups(ug) x 16, x 4 gates = 8 W-tiles:
//   q=0..2 (i,f,g) register-resident (6 tiles, 192 VGPR); q=3 (o) in LDS (16 tiles, 128KB).
// h double-buffered in LDS (2x8KB) -> ONE barrier/step, no read/write race.
// launch_bounds(512,1): a 512-thr block already forces 2 waves/SIMD; asking for
// more (512,2 -> 128-VGPR cap) spilled the whole wreg set to scratch in round 3.
__global__ __launch_bounds__(512, 1)
void lstm_kernel(const float* __restrict__ xT, const float* __restrict__ Wih,
                 const float* __restrict__ bih, const float* __restrict__ bhh,
                 const _Float16* __restrict__ Wpack, u16* __restrict__ hlast)
{
    __shared__ __align__(16) u16 wlds[16][4096];   // 128 KB  o-gate tiles, id = wv*2+ug
    __shared__ __align__(16) u16 hlds[2][4096];    // 16 KB   h ping-pong, XOR-swizzled
    __shared__ float2 bwlds[1024];                 // 8 KB    {b_ih+b_hh, W_ih} per gate-row

    const int tid  = threadIdx.x;
    const int lane = tid & 63;
    const int wv   = tid >> 6;     // 0..7
    const int l15  = lane & 15;
    const int l4   = lane >> 4;
    const int r0   = blockIdx.x * 16;
    const int u0   = wv * 32;

    // ---- prologue ----
    for (int g = tid; g < 1024; g += 512) bwlds[g] = make_float2(bih[g] + bhh[g], Wih[g]);
    for (int i = tid; i < 1024; i += 512) ((u64*)hlds[0])[i] = 0;   // h_0 = 0

    // stage o-gate tiles into LDS (swizzled)
    for (int ch = tid; ch < 8192; ch += 512) {
        const int tl = ch >> 9;            // tile 0..15 (= wv*2+ug)
        const int r  = (ch >> 5) & 15;     // row (unit) in tile
        const int ks = (ch & 31) * 8;      // u16 col start
        const int G  = 768 + (tl >> 1) * 32 + (tl & 1) * 16 + r;
        half8 v = *(const half8*)(Wpack + (size_t)G * NH + ks);
        *(half8*)(&wlds[tl][r * 256 + (ks ^ ((r & 7) << 3))]) = v;
    }

    // register-resident W tiles: ug x {i,f,g}
    half8 wreg[2][3][8];
    #pragma unroll
    for (int ug = 0; ug < 2; ug++)
        #pragma unroll
        for (int q = 0; q < 3; q++) {
            const int G = q * 256 + u0 + ug * 16 + l15;
            #pragma unroll
            for (int kc = 0; kc < 8; kc++)
                wreg[ug][q][kc] = *(const half8*)(Wpack + (size_t)G * NH + kc * 32 + l4 * 8);
        }

    float cst[8];
    #pragma unroll
    for (int i = 0; i < 8; i++) cst[i] = 0.f;

    __syncthreads();

    for (int t = 0; t < NT; t++) {
        const u16* hsrc = hlds[t & 1];
        u16*       hdst = hlds[(t + 1) & 1];
        const floatx4 xv = *(const floatx4*)(xT + (size_t)t * NB + r0 + l4 * 4);

        #pragma unroll
        for (int ug = 0; ug < 2; ug++) {
            floatx4 acc[4];
            #pragma unroll
            for (int q = 0; q < 4; q++) {
                const float2 bw = bwlds[q * 256 + u0 + ug * 16 + l15];
                #pragma unroll
                for (int j = 0; j < 4; j++) acc[q][j] = bw.x + xv[j] * bw.y;
            }
            #pragma unroll
            for (int half_ = 0; half_ < 2; half_++) {
                half8 a[4];
                #pragma unroll
                for (int k2 = 0; k2 < 4; k2++) {
                    const int ks = (half_ * 4 + k2) * 32 + l4 * 8;
                    a[k2] = *(const half8*)(hsrc + l15 * 256 + (ks ^ ((l15 & 7) << 3)));
                }
                #pragma unroll
                for (int k2 = 0; k2 < 4; k2++) {
                    const int kc = half_ * 4 + k2;
                    const int ks = kc * 32 + l4 * 8;
                    acc[0] = mfma16(a[k2], wreg[ug][0][kc], acc[0]);
                    acc[1] = mfma16(a[k2], wreg[ug][1][kc], acc[1]);
                    acc[2] = mfma16(a[k2], wreg[ug][2][kc], acc[2]);
                    const half8 b3 = *(const half8*)(&wlds[wv * 2 + ug][l15 * 256 + (ks ^ ((l15 & 7) << 3))]);
                    acc[3] = mfma16(a[k2], b3, acc[3]);
                }
            }
            // folded pointwise: i*g = (eg-1)/((eg+1)(1+ei)); h = (ec-1)/((ec+1)(1+eo))
            #pragma unroll
            for (int j = 0; j < 4; j++) {
                const float pi = acc[0][j], pf = acc[1][j], pg = acc[2][j], po = acc[3][j];
                const float ei = fexp2(-LOG2E * pi);
                const float ef = fexp2(-LOG2E * pf);
                const float eo = fexp2(-LOG2E * po);
                const float eg = fexp2(TWOL * pg);               // |pg| < 18 -> no overflow
                const float f  = frcp(1.f + ef);
                const float ig = (eg - 1.f) * frcp((eg + 1.f) * (1.f + ei));
                const float cc = f * cst[ug * 4 + j] + ig;
                cst[ug * 4 + j] = cc;
                const float ec = fexp2(fminf(TWOL * cc, 126.f)); // c can grow -> clamp
                const float h  = (ec - 1.f) * frcp((ec + 1.f) * (1.f + eo));
                const int row  = l4 * 4 + j;
                const int unit = u0 + ug * 16 + l15;
                hdst[row * 256 + (unit ^ ((row & 7) << 3))] = __builtin_bit_cast(u16, (_Float16)h);
            }
        }
        __syncthreads();   // h_{t+1} complete; next step reads the other buffer
    }

    // h_T lives in hlds[0] (t=511 wrote buffer (512)&1 == 0)
    for (int i = tid; i < 4096; i += 512) {
        const int row = i >> 8, unit = i & 255;
        hlast[(size_t)(r0 + row) * NH + unit] = hlds[0][row * 256 + (unit ^ ((row & 7) << 3))];
    }
}

// --------------------------------------------------------------- linear ----
// out[2048,512] = h_last(f16) @ W_lin^T + b_lin
__global__ __launch_bounds__(256, 2)
void linear_kernel(const u16* __restrict__ hlast_u, const _Float16* __restrict__ WlinPack,
                   const float* __restrict__ blin, float* __restrict__ out)
{
    const int tid = threadIdx.x;
    const int lane = tid & 63;
    const int wv = tid >> 6;
    const int mi = wv >> 1, ni = wv & 1;
    const int l15 = lane & 15, l4 = lane >> 4;
    const int r0 = (blockIdx.x >> 3) * 32;
    const int o0 = (blockIdx.x & 7) * 64;
    const _Float16* hl = (const _Float16*)hlast_u;
    const int arow = r0 + mi * 16 + l15;

    half8 a[8];
    #pragma unroll
    for (int kc = 0; kc < 8; kc++)
        a[kc] = *(const half8*)(hl + (size_t)arow * NH + kc * 32 + l4 * 8);

    #pragma unroll
    for (int nt = 0; nt < 2; nt++) {
        const int col = o0 + ni * 32 + nt * 16 + l15;
        floatx4 acc = (floatx4){0.f, 0.f, 0.f, 0.f};
        #pragma unroll
        for (int kc = 0; kc < 8; kc++) {
            const half8 b = *(const half8*)(WlinPack + (size_t)col * NH + kc * 32 + l4 * 8);
            acc = mfma16(a[kc], b, acc);
        }
        const float bb = blin[col];
        #pragma unroll
        for (int j = 0; j < 4; j++) {
            const int row = r0 + mi * 16 + l4 * 4 + j;
            out[(size_t)row * NOUT + col] = acc[j] + bb;
        }
    }
}

// --------------------------------------------------------------- launch ----
extern "C" void kernel_launch(void* const* d_in, const int* in_sizes, int n_in,
                              void* d_out, int out_size, void* d_ws, size_t ws_size,
                              hipStream_t stream)
{
    const float* x    = (const float*)d_in[0];
    const float* Wih  = (const float*)d_in[1];
    const float* Whh  = (const float*)d_in[2];
    const float* bih  = (const float*)d_in[3];
    const float* bhh  = (const float*)d_in[4];
    const float* Wlin = (const float*)d_in[5];
    const float* blin = (const float*)d_in[6];

    char* ws = (char*)d_ws;
    _Float16* Wpack    = (_Float16*)(ws);                 // 512 KB
    _Float16* WlinPack = (_Float16*)(ws + (512 << 10));   // 256 KB
    u16*      hlast    = (u16*)(ws + (768 << 10));        // 1 MB
    float*    xT       = (float*)d_out;                   // scratch until linear overwrites

    setup_kernel<<<256, 256, 0, stream>>>(Whh, Wlin, Wpack, WlinPack);
    transpose_kernel<<<dim3(16, 64), 256, 0, stream>>>(x, xT);
    lstm_kernel<<<128, 512, 0, stream>>>(xT, Wih, bih, bhh, Wpack, hlast);
    linear_kernel<<<512, 256, 0, stream>>>(hlast, WlinPack, blin, (float*)d_out);
}